// Round 11
// baseline (61.197 us; speedup 1.0000x reference)
//
#include <hip/hip_runtime.h>
#include <stdint.h>

// PoolerNeighborMap R29: R28 (champion + compute-tap prefetch, 60.9us)
// + per-block ROLE FLIP to balance SIMD issue. Waves map to SIMDs as wv%4;
// with roleC=(wv<2) in every block, ALL compute waves (FMA + ds_read2
// issue) of all 6 resident blocks concentrate on SIMDs 0-1 and all stage
// waves on SIMDs 2-3 (chip VALUBusy 24% = ~48% hot / ~5% cold split).
// Odd blocks (bid&1) now use roleC=(wv>=2): each SIMD hosts ~3 compute +
// ~3 stage waves -> FMA/ds_read2 and gload/vmwait issue spread over all 4
// SIMDs. Pure index remap (cw/sw ordinals); schedule/waits/barriers
// byte-identical to R28.

#define NCH 256
#define NPOOL 10
#define POOLF 6144     // LDS pool floats (24KB)
#define CPB 32

typedef float v2f __attribute__((ext_vector_type(2)));

struct BoxInfo {
    float rx1, ry1, rw, rh;
    int   batch, level;
    int   pad0, pad1;
};

// setup + bitonic sort fused: one block, 512 threads.
__global__ __launch_bounds__(512) void prep_kernel(const float* __restrict__ boxes,
                                                   const int* __restrict__ batch_ids,
                                                   int N, BoxInfo* __restrict__ info,
                                                   float* __restrict__ masks_out,
                                                   int* __restrict__ order) {
    __shared__ unsigned keys[512];
    int t = threadIdx.x;
    unsigned key = 0xFFFFFFFFu - (unsigned)(512 - t);
    if (t < N) {
        float x1 = boxes[t * 4 + 0];
        float y1 = boxes[t * 4 + 1];
        float x2 = boxes[t * 4 + 2];
        float y2 = boxes[t * 4 + 3];
        float w = x2 - x1 + 1.0f;
        float h = y2 - y1 + 1.0f;
        float s = sqrtf(w * h);
        int   lv = 0;
        float mk = 0.25f;
        if (s >= 112.0f) { lv = 1; mk = 0.5f; }
        if (s >= 224.0f) { lv = 2; mk = 1.0f; }
        if (s >= 448.0f) { lv = 3; mk = 2.0f; }
        masks_out[t] = mk;

        float cx = x1 + 0.5f * w;
        float cy = y1 + 0.5f * h;
        float ew = w * 1.5f;
        float eh = h * 1.5f;
        float ex1 = cx - 0.5f * ew;
        float ey1 = cy - 0.5f * eh;
        float ex2 = cx + 0.5f * ew - 1.0f;
        float ey2 = cy + 0.5f * eh - 1.0f;

        const float scales[4] = {0.25f, 0.125f, 0.0625f, 0.03125f};
        float sc = scales[lv];
        float rx1 = ex1 * sc, ry1 = ey1 * sc;
        float rx2 = ex2 * sc, ry2 = ey2 * sc;

        BoxInfo bi;
        bi.rx1 = rx1;
        bi.ry1 = ry1;
        bi.rw = fmaxf(rx2 - rx1, 1.0f);
        bi.rh = fmaxf(ry2 - ry1, 1.0f);
        bi.batch = batch_ids[t];
        bi.level = lv;
        bi.pad0 = 0; bi.pad1 = 0;
        info[t] = bi;

        int yc = (int)fminf(fmaxf(0.5f * (y1 + y2), 0.0f), 2047.0f);
        int b = batch_ids[t] & 1;
        key = ((unsigned)lv << 21) | ((unsigned)b << 20) | ((unsigned)yc << 9) | (unsigned)t;
    }
    keys[t] = key;
    __syncthreads();
    for (int k = 2; k <= 512; k <<= 1) {
        for (int j = k >> 1; j > 0; j >>= 1) {
            int ixj = t ^ j;
            if (ixj > t) {
                unsigned a = keys[t], b2 = keys[ixj];
                bool up = ((t & k) == 0);
                if ((a > b2) == up) { keys[t] = b2; keys[ixj] = a; }
            }
            __syncthreads();
        }
    }
    if (t < N) order[t] = (int)(keys[t] & 511u);
}

__device__ __forceinline__ void load_lds16(const float* g, float* l) {
    __builtin_amdgcn_global_load_lds(
        (const __attribute__((address_space(1))) void*)g,
        (__attribute__((address_space(3))) void*)l, 16, 0, 0);
}
__device__ __forceinline__ void load_lds4(const float* g, float* l) {
    __builtin_amdgcn_global_load_lds(
        (const __attribute__((address_space(1))) void*)g,
        (__attribute__((address_space(3))) void*)l, 4, 0, 0);
}

template<int K> __device__ __forceinline__ void vmwait() {
    if constexpr (K == 0)       asm volatile("s_waitcnt vmcnt(0)" ::: "memory");
    else if constexpr (K == 1)  asm volatile("s_waitcnt vmcnt(1)" ::: "memory");
    else if constexpr (K == 2)  asm volatile("s_waitcnt vmcnt(2)" ::: "memory");
    else if constexpr (K == 3)  asm volatile("s_waitcnt vmcnt(3)" ::: "memory");
    else if constexpr (K == 4)  asm volatile("s_waitcnt vmcnt(4)" ::: "memory");
    else if constexpr (K == 6)  asm volatile("s_waitcnt vmcnt(6)" ::: "memory");
    else if constexpr (K == 8)  asm volatile("s_waitcnt vmcnt(8)" ::: "memory");
    else if constexpr (K == 16) asm volatile("s_waitcnt vmcnt(16)" ::: "memory");
    else if constexpr (K == 24) asm volatile("s_waitcnt vmcnt(24)" ::: "memory");
    else                        asm volatile("s_waitcnt vmcnt(32)" ::: "memory");
}

#define BARR() do {                                             \
    __builtin_amdgcn_s_barrier();                               \
    __builtin_amdgcn_sched_barrier(0);                          \
} while (0)

__global__ __launch_bounds__(256, 8) void roi_kernel(
        const float* __restrict__ f0, const float* __restrict__ f1,
        const float* __restrict__ f2, const float* __restrict__ f3,
        const BoxInfo* __restrict__ info, const int* __restrict__ order,
        float* __restrict__ out) {
    __shared__ __attribute__((aligned(16))) float ldsp[POOLF];
    __shared__ float4 prm[40];
    __shared__ unsigned bm[7];
    __shared__ int dry[40];
    __shared__ int ylist[40];
    __shared__ int xcol[40];

    int bid = blockIdx.x;
    int n = order[bid >> 3];
    int cblk = (bid & 7) * CPB;
    int t = threadIdx.x;
    int wv = t >> 6;
    int lane = t & 63;

    BoxInfo bi = info[n];
    const float* feat;
    int H, W;
    switch (bi.level) {
        case 0:  feat = f0; H = 200; W = 304; break;
        case 1:  feat = f1; H = 100; W = 152; break;
        case 2:  feat = f2; H = 50;  W = 76;  break;
        default: feat = f3; H = 25;  W = 38;  break;
    }
    int HW = H * W;
    bool lv3 = (bi.level == 3);

    // ---- sample params ----
    if (t < 40) {
        bool isY = t < 20;
        int  s = isY ? t : t - 20;
        float R1 = isY ? bi.ry1 : bi.rx1;
        float RL = isY ? bi.rh  : bi.rw;
        float SZ = isY ? (float)H : (float)W;
        float frac = ((float)s + 0.5f) * 0.05f;
        float cpos = R1 + RL * frac;
        float valid = (cpos > -1.0f && cpos < SZ) ? 1.0f : 0.0f;
        float cc = fmaxf(cpos, 0.0f);
        float cf = floorf(cc);
        int lo = (int)fminf(cf, SZ - 1.0f);
        int hi = min(lo + 1, (int)SZ - 1);
        float fr = (cf >= SZ - 1.0f) ? 0.0f : (cc - cf);
        prm[t] = make_float4(__int_as_float(lo), __int_as_float(hi), fr, valid);
    }
    if (t < 7) bm[t] = 0u;
    __syncthreads();

    // ---- mark distinct y rows (dense); x pair cols ----
    int y_t = 0;
    if (t < 40) {
        float4 yp = prm[t >> 1];
        y_t = (t & 1) ? __float_as_int(yp.y) : __float_as_int(yp.x);
        if (!lv3) atomicOr(&bm[y_t >> 5], 1u << (y_t & 31));
    }
    if (t >= 64 && t < 104) {
        int c2 = t - 64;
        xcol[c2] = min(__float_as_int(prm[20 + (c2 >> 1)].x), W - 2) + (c2 & 1);
    }
    __syncthreads();

    // ---- ranks + row list ----
    if (t < 40) {
        if (lv3) {
            dry[t] = y_t;
        } else {
            int wI = y_t >> 5, bI = y_t & 31;
            int r = 0;
            for (int k = 0; k < 6; ++k)
                if (k < wI) r += __popc(bm[k]);
            r += __popc(bm[wI] & ((bI == 0) ? 0u : ((1u << bI) - 1u)));
            dry[t] = r;
            ylist[r] = y_t;
        }
    }
    __syncthreads();

    // ---- tile geometry ----
    int Dy   = dry[39] + 1;
    int xm4  = xcol[0] & ~3;
    int span = xcol[39] - xm4 + 1;
    int SPa  = (span + 3) & ~3;
    int SPad = SPa + (((SPa >> 2) & 1) ? 0 : 4);   // odd granule count
    if (lv3) { xm4 = 0; SPad = 38; }
    int T = Dy * SPad;

    // ---- role flip: odd blocks swap compute/stage wave pairs ----
    int bp = bid & 1;
    bool roleC = bp ? (wv >= 2) : (wv < 2);
    int cw = bp ? (wv - 2) : wv;     // compute ordinal (0/1) when roleC
    int sw = bp ? wv : (wv - 2);     // stage ordinal (0/1) when !roleC

    // ---- stage-wave per-lane source offsets ----
    int vof[8];
    if (!roleC) {
        if (lv3) {
#pragma unroll
            for (int j = 0; j < 8; ++j)
                vof[j] = min(j * 128 + sw * 64 + lane, HW - 1);
        } else {
            int Gp = SPad >> 2;
            int g0 = sw * 64 + lane;
            int r  = g0 / Gp;
            int gc = g0 - r * Gp;
            int q   = 128 / Gp;
            int rem = 128 - q * Gp;
#pragma unroll
            for (int j = 0; j < 6; ++j) {
                int re = min(r, Dy - 1);
                bool pad = (r >= Dy) || ((gc << 2) >= SPa);
                vof[j] = ylist[re] * W + xm4 + (pad ? 0 : (gc << 2));
                r += q; gc += rem;
                if (gc >= Gp) { gc -= Gp; ++r; }
            }
        }
    }

    // ---- compute-wave taps: 8 byte-addresses (4 rows x 2 x-pairs) + weights ----
    bool doOut = roleC && (lane < 50);
    float wy[4];
    float wxA[2], wxB[2];
    unsigned adr[8];
    unsigned lbase = (unsigned)(uintptr_t)(__attribute__((address_space(3))) float*)ldsp;
    if (roleC) {
        int o = cw * 50 + min(lane, 49);
        int py = o / 10, px = o - py * 10;
        int colA0, colA1;
#pragma unroll
        for (int ix = 0; ix < 2; ++ix) {
            float4 xp = prm[20 + 2 * px + ix];
            int x0 = __float_as_int(xp.x);
            float lx = (x0 >= W - 1) ? 1.0f : xp.z;
            float vx = xp.w * 0.25f;
            if (ix == 0) colA0 = xcol[2 * (2 * px)] - xm4;
            else         colA1 = xcol[2 * (2 * px + 1)] - xm4;
            wxA[ix] = vx * (1.0f - lx);
            wxB[ix] = vx * lx;
        }
#pragma unroll
        for (int iy = 0; iy < 2; ++iy) {
            float4 yp = prm[2 * py + iy];
            int r0 = dry[4 * py + 2 * iy]     * SPad;
            int r1 = dry[4 * py + 2 * iy + 1] * SPad;
            adr[(2 * iy) * 2]     = lbase + (unsigned)((r0 + colA0) << 2);
            adr[(2 * iy) * 2 + 1] = lbase + (unsigned)((r0 + colA1) << 2);
            adr[(2 * iy + 1) * 2]     = lbase + (unsigned)((r1 + colA0) << 2);
            adr[(2 * iy + 1) * 2 + 1] = lbase + (unsigned)((r1 + colA1) << 2);
            wy[2 * iy]     = yp.w * (1.0f - yp.z);
            wy[2 * iy + 1] = yp.w * yp.z;
        }
    }

    const float* ub = feat + (size_t)(bi.batch * NCH + cblk) * (size_t)HW;
    size_t HW1 = (size_t)HW;
    float* op;
    {
        int o = cw * 50 + min(lane, 49);
        op = out + ((size_t)n * NCH + cblk) * (NPOOL * NPOOL) + o;
    }

#define STAGED2(GP, BI) do {                                                 \
    const float* g_ = (GP);                                                  \
    float* l_ = ldsp + (BI) * 1024 + sw * 256;                               \
    load_lds16(g_ + vof[0], l_);                                             \
    load_lds16(g_ + vof[1], l_ + 512);                                       \
} while (0)

#define STAGED3N(GP, BI) do {                                                \
    const float* g_ = (GP);                                                  \
    float* l_ = ldsp + (BI) * 1536 + sw * 256;                               \
    load_lds16(g_ + vof[0], l_);                                             \
    load_lds16(g_ + vof[1], l_ + 512);                                       \
    load_lds16(g_ + vof[2], l_ + 1024);                                      \
} while (0)

#define STAGED4(GP, BI) do {                                                 \
    const float* g_ = (GP);                                                  \
    float* l_ = ldsp + (BI) * 2048 + sw * 256;                               \
    load_lds16(g_ + vof[0], l_);                                             \
    load_lds16(g_ + vof[1], l_ + 512);                                       \
    load_lds16(g_ + vof[2], l_ + 1024);                                      \
    load_lds16(g_ + vof[3], l_ + 1536);                                      \
} while (0)

#define STAGED6(GP, BI) do {                                                 \
    const float* g_ = (GP);                                                  \
    float* l_ = ldsp + (BI) * 3072 + sw * 256;                               \
    load_lds16(g_ + vof[0], l_);                                             \
    load_lds16(g_ + vof[1], l_ + 512);                                       \
    load_lds16(g_ + vof[2], l_ + 1024);                                      \
    load_lds16(g_ + vof[3], l_ + 1536);                                      \
    load_lds16(g_ + vof[4], l_ + 2048);                                      \
    load_lds16(g_ + vof[5], l_ + 2560);                                      \
} while (0)

#define STAGE3(GP, BI) do {                                                  \
    const float* g_ = (GP);                                                  \
    float* l_ = ldsp + (BI) * 1024 + sw * 64;                                \
    _Pragma("unroll")                                                        \
    for (int j = 0; j < 8; ++j)                                              \
        load_lds4(g_ + vof[j], l_ + j * 128);                                \
} while (0)

// ---- prefetch primitives: issue ch reads into persistent p0..p7 ----
#define ISSUE8(BUFVv, BI) do {                                               \
    unsigned bb_ = (unsigned)((BI) * (BUFVv) << 2);                          \
    asm volatile("ds_read2_b32 %0, %1 offset0:0 offset1:1"                   \
                 : "=v"(p0) : "v"(adr[0] + bb_));                            \
    asm volatile("ds_read2_b32 %0, %1 offset0:0 offset1:1"                   \
                 : "=v"(p1) : "v"(adr[1] + bb_));                            \
    asm volatile("ds_read2_b32 %0, %1 offset0:0 offset1:1"                   \
                 : "=v"(p2) : "v"(adr[2] + bb_));                            \
    asm volatile("ds_read2_b32 %0, %1 offset0:0 offset1:1"                   \
                 : "=v"(p3) : "v"(adr[3] + bb_));                            \
    asm volatile("ds_read2_b32 %0, %1 offset0:0 offset1:1"                   \
                 : "=v"(p4) : "v"(adr[4] + bb_));                            \
    asm volatile("ds_read2_b32 %0, %1 offset0:0 offset1:1"                   \
                 : "=v"(p5) : "v"(adr[5] + bb_));                            \
    asm volatile("ds_read2_b32 %0, %1 offset0:0 offset1:1"                   \
                 : "=v"(p6) : "v"(adr[6] + bb_));                            \
    asm volatile("ds_read2_b32 %0, %1 offset0:0 offset1:1"                   \
                 : "=v"(p7) : "v"(adr[7] + bb_));                            \
} while (0)

// consume p0..p7 (reads issued previous interval; latency hidden)
#define FMAOUT(OP) do {                                                      \
    asm volatile("s_waitcnt lgkmcnt(0)" ::: "memory");                       \
    __builtin_amdgcn_sched_barrier(0);                                       \
    float a_ = wy[0] * (wxA[0] * p0.x + wxB[0] * p0.y                        \
                      + wxA[1] * p1.x + wxB[1] * p1.y)                       \
             + wy[1] * (wxA[0] * p2.x + wxB[0] * p2.y                        \
                      + wxA[1] * p3.x + wxB[1] * p3.y)                       \
             + wy[2] * (wxA[0] * p4.x + wxB[0] * p4.y                        \
                      + wxA[1] * p5.x + wxB[1] * p5.y)                       \
             + wy[3] * (wxA[0] * p6.x + wxB[0] * p6.y                       \
                      + wxA[1] * p7.x + wxB[1] * p7.y);                      \
    if (doOut) *(OP) = a_;                                                   \
} while (0)

// drain with prefetch: vmwait<K=(30-c)*L> -> BARR -> FMA(ch c) [-> issue c+1]
#define DR1PF(BUFVv, KV, DOISS) do {                                         \
    if (!roleC) vmwait<KV>();                                                \
    BARR();                                                                  \
    if (roleC) { FMAOUT(po); if (DOISS) ISSUE8(BUFVv, cbn); }                \
    po += 100;                                                               \
    if (++cbn == NBv) cbn = 0;                                               \
} while (0)

// prefetch main loop: prologue stages 0..NB-2, vmwait<KPRO=(NB-2)L> (ch0
// landed), BARR, issue ch0 reads. Interval c: vmwait<KP=(NB-3)L> (ch c+1
// landed) -> BARR -> STAGE(ch c+NB-1) || FMA(ch c) + issue reads(ch c+1).
#define RUN1PF(NBv_, BUFVv, SM, KPRO, KP, ...) do {                          \
    const int NBv = NBv_;                                                    \
    if (!roleC) {                                                            \
        _Pragma("unroll")                                                    \
        for (int b = 0; b < NBv - 1; ++b) SM(ub + (size_t)b * HW1, b);       \
        vmwait<KPRO>();                                                      \
    }                                                                        \
    BARR();                                                                  \
    if (roleC) ISSUE8(BUFVv, 0);                                             \
    const float* gs = ub + (size_t)(NBv - 1) * HW1;                          \
    float* po = op;                                                          \
    int sb = NBv - 1, cbn = 1;                                               \
    for (int c = 0; c <= 32 - NBv; ++c) {                                    \
        if (!roleC) vmwait<KP>();                                            \
        BARR();                                                              \
        if (!roleC) SM(gs, sb);                                              \
        if (roleC) { FMAOUT(po); ISSUE8(BUFVv, cbn); }                       \
        po += 100;                                                           \
        gs += HW1;                                                           \
        if (++sb == NBv) sb = 0;                                             \
        if (++cbn == NBv) cbn = 0;                                           \
    }                                                                        \
    __VA_ARGS__                                                              \
} while (0)

// ---- champion non-prefetch forms (R21, verbatim) ----
#define COMPX(BUFVv, BI, OP) do {                                            \
    if (roleC) {                                                             \
        unsigned bb_ = (unsigned)((BI) * (BUFVv) << 2);                      \
        v2f q0, q1, q2, q3, q4, q5, q6, q7;                                  \
        asm volatile("ds_read2_b32 %0, %1 offset0:0 offset1:1"               \
                     : "=v"(q0) : "v"(adr[0] + bb_));                        \
        asm volatile("ds_read2_b32 %0, %1 offset0:0 offset1:1"               \
                     : "=v"(q1) : "v"(adr[1] + bb_));                        \
        asm volatile("ds_read2_b32 %0, %1 offset0:0 offset1:1"               \
                     : "=v"(q2) : "v"(adr[2] + bb_));                        \
        asm volatile("ds_read2_b32 %0, %1 offset0:0 offset1:1"               \
                     : "=v"(q3) : "v"(adr[3] + bb_));                        \
        asm volatile("ds_read2_b32 %0, %1 offset0:0 offset1:1"               \
                     : "=v"(q4) : "v"(adr[4] + bb_));                        \
        asm volatile("ds_read2_b32 %0, %1 offset0:0 offset1:1"               \
                     : "=v"(q5) : "v"(adr[5] + bb_));                        \
        asm volatile("ds_read2_b32 %0, %1 offset0:0 offset1:1"               \
                     : "=v"(q6) : "v"(adr[6] + bb_));                        \
        asm volatile("ds_read2_b32 %0, %1 offset0:0 offset1:1"               \
                     : "=v"(q7) : "v"(adr[7] + bb_));                        \
        asm volatile("s_waitcnt lgkmcnt(0)" ::: "memory");                   \
        __builtin_amdgcn_sched_barrier(0);                                   \
        float a_ = wy[0] * (wxA[0] * q0.x + wxB[0] * q0.y                    \
                          + wxA[1] * q1.x + wxB[1] * q1.y)                   \
                 + wy[1] * (wxA[0] * q2.x + wxB[0] * q2.y                    \
                          + wxA[1] * q3.x + wxB[1] * q3.y)                   \
                 + wy[2] * (wxA[0] * q4.x + wxB[0] * q4.y                    \
                          + wxA[1] * q5.x + wxB[1] * q5.y)                   \
                 + wy[3] * (wxA[0] * q6.x + wxB[0] * q6.y                    \
                          + wxA[1] * q7.x + wxB[1] * q7.y);                  \
        if (doOut) *(OP) = a_;                                               \
    }                                                                        \
} while (0)

#define DR1(BUFVv, KV) do {                                                  \
    if (!roleC) vmwait<KV>();                                                \
    BARR();                                                                  \
    COMPX(BUFVv, cb, po); po += 100;                                         \
    if (++cb == NBv) cb = 0;                                                 \
} while (0)

#define RUN1(NBv_, BUFVv, SM, KW, ...) do {                                  \
    const int NBv = NBv_;                                                    \
    if (!roleC) {                                                            \
        _Pragma("unroll")                                                    \
        for (int b = 0; b < NBv - 1; ++b) SM(ub + (size_t)b * HW1, b);       \
    }                                                                        \
    const float* gs = ub + (size_t)(NBv - 1) * HW1;                          \
    float* po = op;                                                          \
    int sb = NBv - 1, cb = 0;                                                \
    for (int c = 0; c <= 32 - NBv; ++c) {                                    \
        if (!roleC) vmwait<KW>();                                            \
        BARR();                                                              \
        if (!roleC) SM(gs, sb);                                              \
        COMPX(BUFVv, cb, po); po += 100;                                     \
        gs += HW1;                                                           \
        if (++sb == NBv) sb = 0;                                             \
        if (++cb == NBv) cb = 0;                                             \
    }                                                                        \
    __VA_ARGS__                                                              \
} while (0)

#define DRIT(BUFVv, NBv, KSTR) do {                                          \
    if (!roleC) { asm volatile("s_waitcnt vmcnt(" KSTR ")" ::: "memory"); }  \
    BARR(); COMPX(BUFVv, cb, po); po += 100; BARR();                         \
    if (++cb == NBv) cb = 0;                                                 \
} while (0)

#define RUN(NBv, BUFVv, SM, KMAIN, ...) do {                                 \
    if (!roleC) {                                                            \
        _Pragma("unroll")                                                    \
        for (int b = 0; b < NBv - 1; ++b) SM(ub + (size_t)b * HW1, b);       \
    }                                                                        \
    const float* gs = ub + (size_t)(NBv - 1) * HW1;                          \
    float* po = op;                                                          \
    int sb = NBv - 1, cb = 0;                                                \
    for (int c = 0; c <= 32 - NBv; ++c) {                                    \
        if (!roleC) {                                                        \
            SM(gs, sb);                                                      \
            asm volatile("s_waitcnt vmcnt(" KMAIN ")" ::: "memory");         \
        }                                                                    \
        BARR(); COMPX(BUFVv, cb, po); po += 100; BARR();                     \
        gs += HW1;                                                           \
        if (++sb == NBv) sb = 0;                                             \
        if (++cb == NBv) cb = 0;                                             \
    }                                                                        \
    __VA_ARGS__                                                              \
} while (0)

    v2f p0, p1, p2, p3, p4, p5, p6, p7;   // persistent prefetch taps

    if (lv3) {
        // NB=6, L=8: KPRO=32, K'=24; drains (30-c)*8 = 24,16,8,0; last 0
        RUN1PF(6, 1024, STAGE3, 32, 24,
               DR1PF(1024, 24, 1); DR1PF(1024, 16, 1); DR1PF(1024, 8, 1);
               DR1PF(1024, 0, 1);  DR1PF(1024, 0, 0););
    } else if (T <= 1024) {
        // NB=6, L=2: KPRO=8, K'=6; drains 6,4,2,0; last 0
        RUN1PF(6, 1024, STAGED2, 8, 6,
               DR1PF(1024, 6, 1); DR1PF(1024, 4, 1); DR1PF(1024, 2, 1);
               DR1PF(1024, 0, 1); DR1PF(1024, 0, 0););
    } else if (T <= 1536) {
        // NB=4, L=3: KPRO=6, K'=3; drains 3,0; last 0
        RUN1PF(4, 1536, STAGED3N, 6, 3,
               DR1PF(1536, 3, 1); DR1PF(1536, 0, 1); DR1PF(1536, 0, 0););
    } else if (T <= 2048) {
        // champion NB=3 (K'=0 would kill stage lookahead -> no prefetch)
        RUN1(3, 2048, STAGED4, 4,
             DR1(2048, 4); DR1(2048, 0););
    } else {
        RUN(2, 3072, STAGED6, "6",
            DRIT(3072, 2, "0"););
    }

#undef STAGED2
#undef STAGED3N
#undef STAGED4
#undef STAGED6
#undef STAGE3
#undef ISSUE8
#undef FMAOUT
#undef DR1PF
#undef RUN1PF
#undef COMPX
#undef DR1
#undef RUN1
#undef DRIT
#undef RUN
}

extern "C" void kernel_launch(void* const* d_in, const int* in_sizes, int n_in,
                              void* d_out, int out_size, void* d_ws, size_t ws_size,
                              hipStream_t stream) {
    const float* x0 = (const float*)d_in[0];
    const float* x1 = (const float*)d_in[1];
    const float* x2 = (const float*)d_in[2];
    const float* x3 = (const float*)d_in[3];
    const float* boxes = (const float*)d_in[4];
    const int* batch_ids = (const int*)d_in[5];
    int N = in_sizes[4] / 4;

    BoxInfo* info = (BoxInfo*)d_ws;
    int* order = (int*)((char*)d_ws + 512 * sizeof(BoxInfo));
    float* out = (float*)d_out;
    float* masks = out + (size_t)N * NCH * NPOOL * NPOOL;

    prep_kernel<<<1, 512, 0, stream>>>(boxes, batch_ids, N, info, masks, order);

    roi_kernel<<<N * (NCH / CPB), 256, 0, stream>>>(x0, x1, x2, x3, info, order, out);
}

// Round 12
// 61.085 us; speedup vs baseline: 1.0018x; 1.0018x over previous
//
#include <hip/hip_runtime.h>
#include <stdint.h>

// PoolerNeighborMap R30 (final): exact R28 revert — best-measured variant
// (60.9us). R29's per-block role flip was neutral (61.2, within noise);
// reverted to lock the champion binary.
// Structure: R21 5-bucket schedule + compute-wave cross-interval tap
// prefetch (ch c+1's 8 ds_read2 issued at end of interval c into persistent
// regs; lgkm(0) at c+1 finds them complete). Stage-wave wait tightened to
// K'=(NB-3)L so prefetched buffer's global loads land before the issue
// point. Floor argument (12 rounds measured): LDS-gather pipe ~37us/CU busy
// of 61us wall; gather volume & conflict tax algorithm-inherent; all
// overlap levers (residency both ways, barrier-free, pairing, SIMD balance)
// measured neutral-or-worse.

#define NCH 256
#define NPOOL 10
#define POOLF 6144     // LDS pool floats (24KB)
#define CPB 32

typedef float v2f __attribute__((ext_vector_type(2)));

struct BoxInfo {
    float rx1, ry1, rw, rh;
    int   batch, level;
    int   pad0, pad1;
};

// setup + bitonic sort fused: one block, 512 threads.
__global__ __launch_bounds__(512) void prep_kernel(const float* __restrict__ boxes,
                                                   const int* __restrict__ batch_ids,
                                                   int N, BoxInfo* __restrict__ info,
                                                   float* __restrict__ masks_out,
                                                   int* __restrict__ order) {
    __shared__ unsigned keys[512];
    int t = threadIdx.x;
    unsigned key = 0xFFFFFFFFu - (unsigned)(512 - t);
    if (t < N) {
        float x1 = boxes[t * 4 + 0];
        float y1 = boxes[t * 4 + 1];
        float x2 = boxes[t * 4 + 2];
        float y2 = boxes[t * 4 + 3];
        float w = x2 - x1 + 1.0f;
        float h = y2 - y1 + 1.0f;
        float s = sqrtf(w * h);
        int   lv = 0;
        float mk = 0.25f;
        if (s >= 112.0f) { lv = 1; mk = 0.5f; }
        if (s >= 224.0f) { lv = 2; mk = 1.0f; }
        if (s >= 448.0f) { lv = 3; mk = 2.0f; }
        masks_out[t] = mk;

        float cx = x1 + 0.5f * w;
        float cy = y1 + 0.5f * h;
        float ew = w * 1.5f;
        float eh = h * 1.5f;
        float ex1 = cx - 0.5f * ew;
        float ey1 = cy - 0.5f * eh;
        float ex2 = cx + 0.5f * ew - 1.0f;
        float ey2 = cy + 0.5f * eh - 1.0f;

        const float scales[4] = {0.25f, 0.125f, 0.0625f, 0.03125f};
        float sc = scales[lv];
        float rx1 = ex1 * sc, ry1 = ey1 * sc;
        float rx2 = ex2 * sc, ry2 = ey2 * sc;

        BoxInfo bi;
        bi.rx1 = rx1;
        bi.ry1 = ry1;
        bi.rw = fmaxf(rx2 - rx1, 1.0f);
        bi.rh = fmaxf(ry2 - ry1, 1.0f);
        bi.batch = batch_ids[t];
        bi.level = lv;
        bi.pad0 = 0; bi.pad1 = 0;
        info[t] = bi;

        int yc = (int)fminf(fmaxf(0.5f * (y1 + y2), 0.0f), 2047.0f);
        int b = batch_ids[t] & 1;
        key = ((unsigned)lv << 21) | ((unsigned)b << 20) | ((unsigned)yc << 9) | (unsigned)t;
    }
    keys[t] = key;
    __syncthreads();
    for (int k = 2; k <= 512; k <<= 1) {
        for (int j = k >> 1; j > 0; j >>= 1) {
            int ixj = t ^ j;
            if (ixj > t) {
                unsigned a = keys[t], b2 = keys[ixj];
                bool up = ((t & k) == 0);
                if ((a > b2) == up) { keys[t] = b2; keys[ixj] = a; }
            }
            __syncthreads();
        }
    }
    if (t < N) order[t] = (int)(keys[t] & 511u);
}

__device__ __forceinline__ void load_lds16(const float* g, float* l) {
    __builtin_amdgcn_global_load_lds(
        (const __attribute__((address_space(1))) void*)g,
        (__attribute__((address_space(3))) void*)l, 16, 0, 0);
}
__device__ __forceinline__ void load_lds4(const float* g, float* l) {
    __builtin_amdgcn_global_load_lds(
        (const __attribute__((address_space(1))) void*)g,
        (__attribute__((address_space(3))) void*)l, 4, 0, 0);
}

template<int K> __device__ __forceinline__ void vmwait() {
    if constexpr (K == 0)       asm volatile("s_waitcnt vmcnt(0)" ::: "memory");
    else if constexpr (K == 1)  asm volatile("s_waitcnt vmcnt(1)" ::: "memory");
    else if constexpr (K == 2)  asm volatile("s_waitcnt vmcnt(2)" ::: "memory");
    else if constexpr (K == 3)  asm volatile("s_waitcnt vmcnt(3)" ::: "memory");
    else if constexpr (K == 4)  asm volatile("s_waitcnt vmcnt(4)" ::: "memory");
    else if constexpr (K == 6)  asm volatile("s_waitcnt vmcnt(6)" ::: "memory");
    else if constexpr (K == 8)  asm volatile("s_waitcnt vmcnt(8)" ::: "memory");
    else if constexpr (K == 16) asm volatile("s_waitcnt vmcnt(16)" ::: "memory");
    else if constexpr (K == 24) asm volatile("s_waitcnt vmcnt(24)" ::: "memory");
    else                        asm volatile("s_waitcnt vmcnt(32)" ::: "memory");
}

#define BARR() do {                                             \
    __builtin_amdgcn_s_barrier();                               \
    __builtin_amdgcn_sched_barrier(0);                          \
} while (0)

__global__ __launch_bounds__(256, 8) void roi_kernel(
        const float* __restrict__ f0, const float* __restrict__ f1,
        const float* __restrict__ f2, const float* __restrict__ f3,
        const BoxInfo* __restrict__ info, const int* __restrict__ order,
        float* __restrict__ out) {
    __shared__ __attribute__((aligned(16))) float ldsp[POOLF];
    __shared__ float4 prm[40];
    __shared__ unsigned bm[7];
    __shared__ int dry[40];
    __shared__ int ylist[40];
    __shared__ int xcol[40];

    int bid = blockIdx.x;
    int n = order[bid >> 3];
    int cblk = (bid & 7) * CPB;
    int t = threadIdx.x;
    int wv = t >> 6;
    int lane = t & 63;

    BoxInfo bi = info[n];
    const float* feat;
    int H, W;
    switch (bi.level) {
        case 0:  feat = f0; H = 200; W = 304; break;
        case 1:  feat = f1; H = 100; W = 152; break;
        case 2:  feat = f2; H = 50;  W = 76;  break;
        default: feat = f3; H = 25;  W = 38;  break;
    }
    int HW = H * W;
    bool lv3 = (bi.level == 3);

    // ---- sample params ----
    if (t < 40) {
        bool isY = t < 20;
        int  s = isY ? t : t - 20;
        float R1 = isY ? bi.ry1 : bi.rx1;
        float RL = isY ? bi.rh  : bi.rw;
        float SZ = isY ? (float)H : (float)W;
        float frac = ((float)s + 0.5f) * 0.05f;
        float cpos = R1 + RL * frac;
        float valid = (cpos > -1.0f && cpos < SZ) ? 1.0f : 0.0f;
        float cc = fmaxf(cpos, 0.0f);
        float cf = floorf(cc);
        int lo = (int)fminf(cf, SZ - 1.0f);
        int hi = min(lo + 1, (int)SZ - 1);
        float fr = (cf >= SZ - 1.0f) ? 0.0f : (cc - cf);
        prm[t] = make_float4(__int_as_float(lo), __int_as_float(hi), fr, valid);
    }
    if (t < 7) bm[t] = 0u;
    __syncthreads();

    // ---- mark distinct y rows (dense); x pair cols ----
    int y_t = 0;
    if (t < 40) {
        float4 yp = prm[t >> 1];
        y_t = (t & 1) ? __float_as_int(yp.y) : __float_as_int(yp.x);
        if (!lv3) atomicOr(&bm[y_t >> 5], 1u << (y_t & 31));
    }
    if (t >= 64 && t < 104) {
        int c2 = t - 64;
        xcol[c2] = min(__float_as_int(prm[20 + (c2 >> 1)].x), W - 2) + (c2 & 1);
    }
    __syncthreads();

    // ---- ranks + row list ----
    if (t < 40) {
        if (lv3) {
            dry[t] = y_t;
        } else {
            int wI = y_t >> 5, bI = y_t & 31;
            int r = 0;
            for (int k = 0; k < 6; ++k)
                if (k < wI) r += __popc(bm[k]);
            r += __popc(bm[wI] & ((bI == 0) ? 0u : ((1u << bI) - 1u)));
            dry[t] = r;
            ylist[r] = y_t;
        }
    }
    __syncthreads();

    // ---- tile geometry ----
    int Dy   = dry[39] + 1;
    int xm4  = xcol[0] & ~3;
    int span = xcol[39] - xm4 + 1;
    int SPa  = (span + 3) & ~3;
    int SPad = SPa + (((SPa >> 2) & 1) ? 0 : 4);   // odd granule count
    if (lv3) { xm4 = 0; SPad = 38; }
    int T = Dy * SPad;

    bool roleC = (wv < 2);

    // ---- stage-wave per-lane source offsets ----
    int vof[8];
    if (!roleC) {
        if (lv3) {
#pragma unroll
            for (int j = 0; j < 8; ++j)
                vof[j] = min(j * 128 + (wv - 2) * 64 + lane, HW - 1);
        } else {
            int Gp = SPad >> 2;
            int g0 = (wv - 2) * 64 + lane;
            int r  = g0 / Gp;
            int gc = g0 - r * Gp;
            int q   = 128 / Gp;
            int rem = 128 - q * Gp;
#pragma unroll
            for (int j = 0; j < 6; ++j) {
                int re = min(r, Dy - 1);
                bool pad = (r >= Dy) || ((gc << 2) >= SPa);
                vof[j] = ylist[re] * W + xm4 + (pad ? 0 : (gc << 2));
                r += q; gc += rem;
                if (gc >= Gp) { gc -= Gp; ++r; }
            }
        }
    }

    // ---- compute-wave taps: 8 byte-addresses (4 rows x 2 x-pairs) + weights ----
    bool doOut = roleC && (lane < 50);
    float wy[4];
    float wxA[2], wxB[2];
    unsigned adr[8];
    unsigned lbase = (unsigned)(uintptr_t)(__attribute__((address_space(3))) float*)ldsp;
    if (roleC) {
        int o = wv * 50 + min(lane, 49);
        int py = o / 10, px = o - py * 10;
        int colA0, colA1;
#pragma unroll
        for (int ix = 0; ix < 2; ++ix) {
            float4 xp = prm[20 + 2 * px + ix];
            int x0 = __float_as_int(xp.x);
            float lx = (x0 >= W - 1) ? 1.0f : xp.z;
            float vx = xp.w * 0.25f;
            if (ix == 0) colA0 = xcol[2 * (2 * px)] - xm4;
            else         colA1 = xcol[2 * (2 * px + 1)] - xm4;
            wxA[ix] = vx * (1.0f - lx);
            wxB[ix] = vx * lx;
        }
#pragma unroll
        for (int iy = 0; iy < 2; ++iy) {
            float4 yp = prm[2 * py + iy];
            int r0 = dry[4 * py + 2 * iy]     * SPad;
            int r1 = dry[4 * py + 2 * iy + 1] * SPad;
            adr[(2 * iy) * 2]     = lbase + (unsigned)((r0 + colA0) << 2);
            adr[(2 * iy) * 2 + 1] = lbase + (unsigned)((r0 + colA1) << 2);
            adr[(2 * iy + 1) * 2]     = lbase + (unsigned)((r1 + colA0) << 2);
            adr[(2 * iy + 1) * 2 + 1] = lbase + (unsigned)((r1 + colA1) << 2);
            wy[2 * iy]     = yp.w * (1.0f - yp.z);
            wy[2 * iy + 1] = yp.w * yp.z;
        }
    }

    const float* ub = feat + (size_t)(bi.batch * NCH + cblk) * (size_t)HW;
    size_t HW1 = (size_t)HW;
    float* op;
    {
        int o = wv * 50 + min(lane, 49);
        op = out + ((size_t)n * NCH + cblk) * (NPOOL * NPOOL) + o;
    }

#define STAGED2(GP, BI) do {                                                 \
    const float* g_ = (GP);                                                  \
    float* l_ = ldsp + (BI) * 1024 + (wv - 2) * 256;                         \
    load_lds16(g_ + vof[0], l_);                                             \
    load_lds16(g_ + vof[1], l_ + 512);                                       \
} while (0)

#define STAGED3N(GP, BI) do {                                                \
    const float* g_ = (GP);                                                  \
    float* l_ = ldsp + (BI) * 1536 + (wv - 2) * 256;                         \
    load_lds16(g_ + vof[0], l_);                                             \
    load_lds16(g_ + vof[1], l_ + 512);                                       \
    load_lds16(g_ + vof[2], l_ + 1024);                                      \
} while (0)

#define STAGED4(GP, BI) do {                                                 \
    const float* g_ = (GP);                                                  \
    float* l_ = ldsp + (BI) * 2048 + (wv - 2) * 256;                         \
    load_lds16(g_ + vof[0], l_);                                             \
    load_lds16(g_ + vof[1], l_ + 512);                                       \
    load_lds16(g_ + vof[2], l_ + 1024);                                      \
    load_lds16(g_ + vof[3], l_ + 1536);                                      \
} while (0)

#define STAGED6(GP, BI) do {                                                 \
    const float* g_ = (GP);                                                  \
    float* l_ = ldsp + (BI) * 3072 + (wv - 2) * 256;                         \
    load_lds16(g_ + vof[0], l_);                                             \
    load_lds16(g_ + vof[1], l_ + 512);                                       \
    load_lds16(g_ + vof[2], l_ + 1024);                                      \
    load_lds16(g_ + vof[3], l_ + 1536);                                      \
    load_lds16(g_ + vof[4], l_ + 2048);                                      \
    load_lds16(g_ + vof[5], l_ + 2560);                                      \
} while (0)

#define STAGE3(GP, BI) do {                                                  \
    const float* g_ = (GP);                                                  \
    float* l_ = ldsp + (BI) * 1024 + (wv - 2) * 64;                          \
    _Pragma("unroll")                                                        \
    for (int j = 0; j < 8; ++j)                                              \
        load_lds4(g_ + vof[j], l_ + j * 128);                                \
} while (0)

// ---- prefetch primitives: issue ch reads into persistent p0..p7 ----
#define ISSUE8(BUFVv, BI) do {                                               \
    unsigned bb_ = (unsigned)((BI) * (BUFVv) << 2);                          \
    asm volatile("ds_read2_b32 %0, %1 offset0:0 offset1:1"                   \
                 : "=v"(p0) : "v"(adr[0] + bb_));                            \
    asm volatile("ds_read2_b32 %0, %1 offset0:0 offset1:1"                   \
                 : "=v"(p1) : "v"(adr[1] + bb_));                            \
    asm volatile("ds_read2_b32 %0, %1 offset0:0 offset1:1"                   \
                 : "=v"(p2) : "v"(adr[2] + bb_));                            \
    asm volatile("ds_read2_b32 %0, %1 offset0:0 offset1:1"                   \
                 : "=v"(p3) : "v"(adr[3] + bb_));                            \
    asm volatile("ds_read2_b32 %0, %1 offset0:0 offset1:1"                   \
                 : "=v"(p4) : "v"(adr[4] + bb_));                            \
    asm volatile("ds_read2_b32 %0, %1 offset0:0 offset1:1"                   \
                 : "=v"(p5) : "v"(adr[5] + bb_));                            \
    asm volatile("ds_read2_b32 %0, %1 offset0:0 offset1:1"                   \
                 : "=v"(p6) : "v"(adr[6] + bb_));                            \
    asm volatile("ds_read2_b32 %0, %1 offset0:0 offset1:1"                   \
                 : "=v"(p7) : "v"(adr[7] + bb_));                            \
} while (0)

// consume p0..p7 (reads issued previous interval; latency hidden)
#define FMAOUT(OP) do {                                                      \
    asm volatile("s_waitcnt lgkmcnt(0)" ::: "memory");                       \
    __builtin_amdgcn_sched_barrier(0);                                       \
    float a_ = wy[0] * (wxA[0] * p0.x + wxB[0] * p0.y                        \
                      + wxA[1] * p1.x + wxB[1] * p1.y)                       \
             + wy[1] * (wxA[0] * p2.x + wxB[0] * p2.y                        \
                      + wxA[1] * p3.x + wxB[1] * p3.y)                       \
             + wy[2] * (wxA[0] * p4.x + wxB[0] * p4.y                        \
                      + wxA[1] * p5.x + wxB[1] * p5.y)                       \
             + wy[3] * (wxA[0] * p6.x + wxB[0] * p6.y                       \
                      + wxA[1] * p7.x + wxB[1] * p7.y);                      \
    if (doOut) *(OP) = a_;                                                   \
} while (0)

// drain with prefetch: vmwait<K=(30-c)*L> -> BARR -> FMA(ch c) [-> issue c+1]
#define DR1PF(BUFVv, KV, DOISS) do {                                         \
    if (!roleC) vmwait<KV>();                                                \
    BARR();                                                                  \
    if (roleC) { FMAOUT(po); if (DOISS) ISSUE8(BUFVv, cbn); }                \
    po += 100;                                                               \
    if (++cbn == NBv) cbn = 0;                                               \
} while (0)

// prefetch main loop: prologue stages 0..NB-2, vmwait<KPRO=(NB-2)L> (ch0
// landed), BARR, issue ch0 reads. Interval c: vmwait<KP=(NB-3)L> (ch c+1
// landed) -> BARR -> STAGE(ch c+NB-1) || FMA(ch c) + issue reads(ch c+1).
#define RUN1PF(NBv_, BUFVv, SM, KPRO, KP, ...) do {                          \
    const int NBv = NBv_;                                                    \
    if (!roleC) {                                                            \
        _Pragma("unroll")                                                    \
        for (int b = 0; b < NBv - 1; ++b) SM(ub + (size_t)b * HW1, b);       \
        vmwait<KPRO>();                                                      \
    }                                                                        \
    BARR();                                                                  \
    if (roleC) ISSUE8(BUFVv, 0);                                             \
    const float* gs = ub + (size_t)(NBv - 1) * HW1;                          \
    float* po = op;                                                          \
    int sb = NBv - 1, cbn = 1;                                               \
    for (int c = 0; c <= 32 - NBv; ++c) {                                    \
        if (!roleC) vmwait<KP>();                                            \
        BARR();                                                              \
        if (!roleC) SM(gs, sb);                                              \
        if (roleC) { FMAOUT(po); ISSUE8(BUFVv, cbn); }                       \
        po += 100;                                                           \
        gs += HW1;                                                           \
        if (++sb == NBv) sb = 0;                                             \
        if (++cbn == NBv) cbn = 0;                                           \
    }                                                                        \
    __VA_ARGS__                                                              \
} while (0)

// ---- champion non-prefetch forms (R21, verbatim) ----
#define COMPX(BUFVv, BI, OP) do {                                            \
    if (roleC) {                                                             \
        unsigned bb_ = (unsigned)((BI) * (BUFVv) << 2);                      \
        v2f q0, q1, q2, q3, q4, q5, q6, q7;                                  \
        asm volatile("ds_read2_b32 %0, %1 offset0:0 offset1:1"               \
                     : "=v"(q0) : "v"(adr[0] + bb_));                        \
        asm volatile("ds_read2_b32 %0, %1 offset0:0 offset1:1"               \
                     : "=v"(q1) : "v"(adr[1] + bb_));                        \
        asm volatile("ds_read2_b32 %0, %1 offset0:0 offset1:1"               \
                     : "=v"(q2) : "v"(adr[2] + bb_));                        \
        asm volatile("ds_read2_b32 %0, %1 offset0:0 offset1:1"               \
                     : "=v"(q3) : "v"(adr[3] + bb_));                        \
        asm volatile("ds_read2_b32 %0, %1 offset0:0 offset1:1"               \
                     : "=v"(q4) : "v"(adr[4] + bb_));                        \
        asm volatile("ds_read2_b32 %0, %1 offset0:0 offset1:1"               \
                     : "=v"(q5) : "v"(adr[5] + bb_));                        \
        asm volatile("ds_read2_b32 %0, %1 offset0:0 offset1:1"               \
                     : "=v"(q6) : "v"(adr[6] + bb_));                        \
        asm volatile("ds_read2_b32 %0, %1 offset0:0 offset1:1"               \
                     : "=v"(q7) : "v"(adr[7] + bb_));                        \
        asm volatile("s_waitcnt lgkmcnt(0)" ::: "memory");                   \
        __builtin_amdgcn_sched_barrier(0);                                   \
        float a_ = wy[0] * (wxA[0] * q0.x + wxB[0] * q0.y                    \
                          + wxA[1] * q1.x + wxB[1] * q1.y)                   \
                 + wy[1] * (wxA[0] * q2.x + wxB[0] * q2.y                    \
                          + wxA[1] * q3.x + wxB[1] * q3.y)                   \
                 + wy[2] * (wxA[0] * q4.x + wxB[0] * q4.y                    \
                          + wxA[1] * q5.x + wxB[1] * q5.y)                   \
                 + wy[3] * (wxA[0] * q6.x + wxB[0] * q6.y                    \
                          + wxA[1] * q7.x + wxB[1] * q7.y);                  \
        if (doOut) *(OP) = a_;                                               \
    }                                                                        \
} while (0)

#define DR1(BUFVv, KV) do {                                                  \
    if (!roleC) vmwait<KV>();                                                \
    BARR();                                                                  \
    COMPX(BUFVv, cb, po); po += 100;                                         \
    if (++cb == NBv) cb = 0;                                                 \
} while (0)

#define RUN1(NBv_, BUFVv, SM, KW, ...) do {                                  \
    const int NBv = NBv_;                                                    \
    if (!roleC) {                                                            \
        _Pragma("unroll")                                                    \
        for (int b = 0; b < NBv - 1; ++b) SM(ub + (size_t)b * HW1, b);       \
    }                                                                        \
    const float* gs = ub + (size_t)(NBv - 1) * HW1;                          \
    float* po = op;                                                          \
    int sb = NBv - 1, cb = 0;                                                \
    for (int c = 0; c <= 32 - NBv; ++c) {                                    \
        if (!roleC) vmwait<KW>();                                            \
        BARR();                                                              \
        if (!roleC) SM(gs, sb);                                              \
        COMPX(BUFVv, cb, po); po += 100;                                     \
        gs += HW1;                                                           \
        if (++sb == NBv) sb = 0;                                             \
        if (++cb == NBv) cb = 0;                                             \
    }                                                                        \
    __VA_ARGS__                                                              \
} while (0)

#define DRIT(BUFVv, NBv, KSTR) do {                                          \
    if (!roleC) { asm volatile("s_waitcnt vmcnt(" KSTR ")" ::: "memory"); }  \
    BARR(); COMPX(BUFVv, cb, po); po += 100; BARR();                         \
    if (++cb == NBv) cb = 0;                                                 \
} while (0)

#define RUN(NBv, BUFVv, SM, KMAIN, ...) do {                                 \
    if (!roleC) {                                                            \
        _Pragma("unroll")                                                    \
        for (int b = 0; b < NBv - 1; ++b) SM(ub + (size_t)b * HW1, b);       \
    }                                                                        \
    const float* gs = ub + (size_t)(NBv - 1) * HW1;                          \
    float* po = op;                                                          \
    int sb = NBv - 1, cb = 0;                                                \
    for (int c = 0; c <= 32 - NBv; ++c) {                                    \
        if (!roleC) {                                                        \
            SM(gs, sb);                                                      \
            asm volatile("s_waitcnt vmcnt(" KMAIN ")" ::: "memory");         \
        }                                                                    \
        BARR(); COMPX(BUFVv, cb, po); po += 100; BARR();                     \
        gs += HW1;                                                           \
        if (++sb == NBv) sb = 0;                                             \
        if (++cb == NBv) cb = 0;                                             \
    }                                                                        \
    __VA_ARGS__                                                              \
} while (0)

    v2f p0, p1, p2, p3, p4, p5, p6, p7;   // persistent prefetch taps

    if (lv3) {
        // NB=6, L=8: KPRO=32, K'=24; drains (30-c)*8 = 24,16,8,0; last 0
        RUN1PF(6, 1024, STAGE3, 32, 24,
               DR1PF(1024, 24, 1); DR1PF(1024, 16, 1); DR1PF(1024, 8, 1);
               DR1PF(1024, 0, 1);  DR1PF(1024, 0, 0););
    } else if (T <= 1024) {
        // NB=6, L=2: KPRO=8, K'=6; drains 6,4,2,0; last 0
        RUN1PF(6, 1024, STAGED2, 8, 6,
               DR1PF(1024, 6, 1); DR1PF(1024, 4, 1); DR1PF(1024, 2, 1);
               DR1PF(1024, 0, 1); DR1PF(1024, 0, 0););
    } else if (T <= 1536) {
        // NB=4, L=3: KPRO=6, K'=3; drains 3,0; last 0
        RUN1PF(4, 1536, STAGED3N, 6, 3,
               DR1PF(1536, 3, 1); DR1PF(1536, 0, 1); DR1PF(1536, 0, 0););
    } else if (T <= 2048) {
        // champion NB=3 (K'=0 would kill stage lookahead -> no prefetch)
        RUN1(3, 2048, STAGED4, 4,
             DR1(2048, 4); DR1(2048, 0););
    } else {
        RUN(2, 3072, STAGED6, "6",
            DRIT(3072, 2, "0"););
    }

#undef STAGED2
#undef STAGED3N
#undef STAGED4
#undef STAGED6
#undef STAGE3
#undef ISSUE8
#undef FMAOUT
#undef DR1PF
#undef RUN1PF
#undef COMPX
#undef DR1
#undef RUN1
#undef DRIT
#undef RUN
}

extern "C" void kernel_launch(void* const* d_in, const int* in_sizes, int n_in,
                              void* d_out, int out_size, void* d_ws, size_t ws_size,
                              hipStream_t stream) {
    const float* x0 = (const float*)d_in[0];
    const float* x1 = (const float*)d_in[1];
    const float* x2 = (const float*)d_in[2];
    const float* x3 = (const float*)d_in[3];
    const float* boxes = (const float*)d_in[4];
    const int* batch_ids = (const int*)d_in[5];
    int N = in_sizes[4] / 4;

    BoxInfo* info = (BoxInfo*)d_ws;
    int* order = (int*)((char*)d_ws + 512 * sizeof(BoxInfo));
    float* out = (float*)d_out;
    float* masks = out + (size_t)N * NCH * NPOOL * NPOOL;

    prep_kernel<<<1, 512, 0, stream>>>(boxes, batch_ids, N, info, masks, order);

    roi_kernel<<<N * (NCH / CPB), 256, 0, stream>>>(x0, x1, x2, x3, info, order, out);
}